// Round 13
// baseline (535.206 us; speedup 1.0000x reference)
//
#include <hip/hip_runtime.h>
#include <hip/hip_bf16.h>

// ---------------------------------------------------------------------------
// ParallelLlamaRingAttention on MI355X (gfx950)
//   hidden[S=2048,B=2,4096] @ w_qkv[4096,6144] -> qkv
//   full (non-causal) GQA flash attention (NH=32, NKV=8, HD=128)
//   attn[4096,4096] @ w_o[4096,4096] -> out (fp32)
// GEMM1: 128x192 BK=64, 80 KB LDS -> 2 blocks/CU, 1024 blocks (r10-proven).
// GEMM2: 256x256 BK=64, 4-phase, counted vmcnt(4) (r8-proven).
// ATTN v3: 4 waves x QBLK=32 q-rows (2x arithmetic intensity: K/V fragment
//   reads and barriers amortized over 2 row-halves), 80 KB LDS, VGPR<=256.
// ---------------------------------------------------------------------------

typedef __bf16 bf16x8 __attribute__((ext_vector_type(8)));
typedef float f32x4 __attribute__((ext_vector_type(4)));
typedef unsigned short u16;
typedef u16 u16x4 __attribute__((ext_vector_type(4)));
typedef u16 u16x8 __attribute__((ext_vector_type(8)));
typedef unsigned int u32;

#define SEQ    2048
#define BATCH  2
#define NROWS  4096      // S*B
#define DM     4096
#define QKVC   6144      // (32+16)*128
// log2e / sqrt(HD): softmax runs in exp2 domain
#define QSCALE (0.08838834764831845f * 1.4426950408889634f)

__device__ __forceinline__ u16 f2bf(float f) {
  union { float f; u32 u; } v; v.f = f;
  u32 r = v.u + 0x7fffu + ((v.u >> 16) & 1u);   // RNE
  return (u16)(r >> 16);
}

__device__ __forceinline__ void gload16(const void* g, void* l) {
  __builtin_amdgcn_global_load_lds(
      (const __attribute__((address_space(1))) unsigned int*)g,
      (__attribute__((address_space(3))) unsigned int*)l, 16, 0, 0);
}

// ---------------- fp32 -> bf16 elementwise ----------------
__global__ __launch_bounds__(256) void conv_f32_bf16(
    const float* __restrict__ in, u16* __restrict__ out) {
  size_t i = ((size_t)blockIdx.x * 256 + threadIdx.x) * 8;
  float4 a = *(const float4*)(in + i);
  float4 b = *(const float4*)(in + i + 4);
  u16x8 o;
  o[0] = f2bf(a.x); o[1] = f2bf(a.y); o[2] = f2bf(a.z); o[3] = f2bf(a.w);
  o[4] = f2bf(b.x); o[5] = f2bf(b.y); o[6] = f2bf(b.z); o[7] = f2bf(b.w);
  *(u16x8*)(out + i) = o;
}

// ---------------- fp32 [K][N] -> bf16 [N][K] transpose ----------------
__global__ __launch_bounds__(256) void transpose_f32_bf16(
    const float* __restrict__ in, u16* __restrict__ out, int K, int N) {
  __shared__ u16 tile[64][65];
  const int k0 = blockIdx.y * 64, n0 = blockIdx.x * 64;
  const int t = threadIdx.x;
#pragma unroll
  for (int i = 0; i < 4; ++i) {
    int slot = i * 256 + t;
    int r = slot >> 4, cq = slot & 15;
    float4 v = *(const float4*)(in + (size_t)(k0 + r) * N + n0 + cq * 4);
    tile[cq * 4 + 0][r] = f2bf(v.x);
    tile[cq * 4 + 1][r] = f2bf(v.y);
    tile[cq * 4 + 2][r] = f2bf(v.z);
    tile[cq * 4 + 3][r] = f2bf(v.w);
  }
  __syncthreads();
#pragma unroll
  for (int i = 0; i < 2; ++i) {
    int slot = i * 256 + t;
    int n = slot >> 3, q = slot & 7;
    u16x8 o;
#pragma unroll
    for (int e = 0; e < 8; ++e) o[e] = tile[n][q * 8 + e];
    *(u16x8*)(out + (size_t)(n0 + n) * K + k0 + q * 8) = o;
  }
}

// ---------------- bf16 V [s][b][kvh][d] -> Vt [(b*8+kvh)*128+d][s] ----------
__global__ __launch_bounds__(256) void vtrans(
    const u16* __restrict__ qkv, u16* __restrict__ vt) {
  __shared__ u16 tile[64][66];
  const int s0 = blockIdx.x * 64, d0 = blockIdx.y * 64;
  const int z = blockIdx.z;            // b*8+kvh
  const int b = z >> 3, kvh = z & 7;
  const int t = threadIdx.x;
#pragma unroll
  for (int i = 0; i < 2; ++i) {
    int chunk = i * 256 + t;
    int r = chunk >> 3, q = chunk & 7;
    u16x8 v = *(const u16x8*)&qkv[(size_t)((s0 + r) * 2 + b) * QKVC + 5120 + kvh * 128 + d0 + q * 8];
#pragma unroll
    for (int e = 0; e < 8; ++e) tile[r][q * 8 + e] = v[e];
  }
  __syncthreads();
#pragma unroll
  for (int i = 0; i < 2; ++i) {
    int chunk = i * 256 + t;
    int d = chunk >> 3, q = chunk & 7;
    u16x8 o;
#pragma unroll
    for (int e = 0; e < 8; ++e) o[e] = tile[q * 8 + e][d];
    *(u16x8*)&vt[(size_t)(z * 128 + d0 + d) * SEQ + s0 + q * 8] = o;
  }
}

// ---------------- bf16 GEMM 128x192: C = A[M,K] * B^T[N,K] ------------------
template <int CBF16, int SCALEQ>
__global__ __launch_bounds__(512, 4) void gemm128(
    const u16* __restrict__ A, const u16* __restrict__ B,
    void* __restrict__ C, int M, int N, int K, int nby) {
  __shared__ u16 As[2 * 8192];    // [2][128][64] 32 KB
  __shared__ u16 Bs[2 * 12288];   // [2][192][64] 48 KB
  const int t = threadIdx.x;
  const int w = t >> 6, l = t & 63;
  const int g = l >> 4, c = l & 15;
  const int wm = w >> 2, wn = w & 3;

  const int nwg = gridDim.x;
  const int sid = (blockIdx.x & 7) * (nwg >> 3) + (blockIdx.x >> 3);
  const int by = sid % nby, bx = sid / nby;
  const int m0 = by * 128, n0 = bx * 192;

  const int gsrc = (l & 7) ^ (l >> 3);
  const u16* pA = A + (size_t)(m0 + w * 8 + (l >> 3)) * K + gsrc * 8;
  const u16* pB = B + (size_t)(n0 + w * 8 + (l >> 3)) * K + gsrc * 8;

#define STG128(tt) do { int d_ = (tt) & 1;                                  \
    _Pragma("unroll")                                                       \
    for (int u = 0; u < 2; ++u)                                             \
      gload16(pA + (size_t)(u * 64) * K + (size_t)(tt) * 64,                \
              &As[d_ * 8192 + u * 4096 + w * 512]);                         \
    _Pragma("unroll")                                                       \
    for (int u = 0; u < 3; ++u)                                             \
      gload16(pB + (size_t)(u * 64) * K + (size_t)(tt) * 64,                \
              &Bs[d_ * 12288 + u * 4096 + w * 512]); } while (0)

  const int xr0 = ((0 + g) ^ (c & 7)) << 3;
  const int xr1 = ((4 + g) ^ (c & 7)) << 3;

  const f32x4 fz = {0.f, 0.f, 0.f, 0.f};
  f32x4 acc[4][3];
#pragma unroll
  for (int m = 0; m < 4; ++m)
#pragma unroll
    for (int n = 0; n < 3; ++n) acc[m][n] = fz;

  const int nkt = K >> 6;
  STG128(0);
  for (int tt = 0; tt < nkt; ++tt) {
    const int d = tt & 1;
    if (tt + 1 < nkt) {
      STG128(tt + 1);
      asm volatile("s_waitcnt vmcnt(5)" ::: "memory");
    } else {
      asm volatile("s_waitcnt vmcnt(0)" ::: "memory");
    }
    __builtin_amdgcn_sched_barrier(0);
    __builtin_amdgcn_s_barrier();

    const u16* aT = &As[d * 8192 + (wm * 64 + c) * 64];
    const u16* bT = &Bs[d * 12288 + (wn * 48 + c) * 64];
    bf16x8 av[4][2], bv[3][2];
#pragma unroll
    for (int m = 0; m < 4; ++m) {
      av[m][0] = *(const bf16x8*)(aT + m * 1024 + xr0);
      av[m][1] = *(const bf16x8*)(aT + m * 1024 + xr1);
    }
#pragma unroll
    for (int n = 0; n < 3; ++n) {
      bv[n][0] = *(const bf16x8*)(bT + n * 1024 + xr0);
      bv[n][1] = *(const bf16x8*)(bT + n * 1024 + xr1);
    }
    __builtin_amdgcn_s_setprio(1);
#pragma unroll
    for (int kk = 0; kk < 2; ++kk)
#pragma unroll
      for (int m = 0; m < 4; ++m)
#pragma unroll
        for (int n = 0; n < 3; ++n)
          acc[m][n] = __builtin_amdgcn_mfma_f32_16x16x32_bf16(
              av[m][kk], bv[n][kk], acc[m][n], 0, 0, 0);
    __builtin_amdgcn_s_setprio(0);
    __builtin_amdgcn_s_barrier();
  }
#undef STG128

#pragma unroll
  for (int m = 0; m < 4; ++m)
#pragma unroll
    for (int n = 0; n < 3; ++n) {
      int row = m0 + wm * 64 + m * 16 + g * 4;
      int col = n0 + wn * 48 + n * 16 + c;
      float sc = (SCALEQ && col < 4096) ? QSCALE : 1.0f;
#pragma unroll
      for (int r = 0; r < 4; ++r) {
        float x = acc[m][n][r] * sc;
        if (CBF16) ((u16*)C)[(size_t)(row + r) * N + col] = f2bf(x);
        else       ((float*)C)[(size_t)(row + r) * N + col] = x;
      }
    }
}

// ---------------- bf16 GEMM 256x256 (4-phase, unpinned barriers) ------------
template <int CBF16, int SCALEQ>
__global__ __launch_bounds__(512, 2) void gemm256(
    const u16* __restrict__ A, const u16* __restrict__ B,
    void* __restrict__ C, int M, int N, int K, int nby) {
  __shared__ u16 As[2 * 2 * 8192];   // 64 KB
  __shared__ u16 Bs[2 * 2 * 8192];   // 64 KB
  const int t = threadIdx.x;
  const int w = t >> 6, l = t & 63;
  const int g = l >> 4, c = l & 15;
  const int wm = w >> 2, wn = w & 3;

  const int nwg = gridDim.x;
  const int sid = (blockIdx.x & 7) * (nwg >> 3) + (blockIdx.x >> 3);
  const int by = sid % nby, bx = sid / nby;
  const int m0 = by * 256, n0 = bx * 256;

  const int gsrc = (l & 7) ^ (l >> 3);
  const u16* pA = A + (size_t)(m0 + w * 8 + (l >> 3)) * K + gsrc * 8;
  const u16* pB = B + (size_t)(n0 + w * 8 + (l >> 3)) * K + gsrc * 8;

#define STG_A(h, tt) do { int d_ = (tt) & 1;                                    \
    gload16(pA + (size_t)((h) * 128) * K + (tt) * 64,                           \
            &As[(d_ * 2 + (h)) * 8192 + w * 512]);                              \
    gload16(pA + (size_t)((h) * 128 + 64) * K + (tt) * 64,                      \
            &As[(d_ * 2 + (h)) * 8192 + 4096 + w * 512]); } while (0)
#define STG_B(h, tt) do { int d_ = (tt) & 1;                                    \
    gload16(pB + (size_t)((h) * 128) * K + (tt) * 64,                           \
            &Bs[(d_ * 2 + (h)) * 8192 + w * 512]);                              \
    gload16(pB + (size_t)((h) * 128 + 64) * K + (tt) * 64,                      \
            &Bs[(d_ * 2 + (h)) * 8192 + 4096 + w * 512]); } while (0)

  const u16* aRd = &As[wm * 8192 + c * 64];
  const u16* bRd = &Bs[(wn >> 1) * 8192 + ((wn & 1) * 64 + c) * 64];
  const int xr0 = ((0 + g) ^ (c & 7)) << 3;
  const int xr1 = ((4 + g) ^ (c & 7)) << 3;

  const f32x4 fz = {0.f, 0.f, 0.f, 0.f};
  f32x4 acc[8][4];
#pragma unroll
  for (int mi = 0; mi < 8; ++mi)
#pragma unroll
    for (int nj = 0; nj < 4; ++nj) acc[mi][nj] = fz;

  const int nkt = K >> 6;
  STG_A(0, 0); STG_A(1, 0); STG_B(0, 0); STG_B(1, 0);
  STG_B(0, 1); STG_B(1, 1);
  asm volatile("s_waitcnt vmcnt(4)" ::: "memory");
  __builtin_amdgcn_sched_barrier(0);
  __builtin_amdgcn_s_barrier();

  for (int tt = 0; tt < nkt; ++tt) {
    const int d = tt & 1;
    const u16* aT = aRd + d * 16384;
    const u16* bT = bRd + d * 16384;
    bf16x8 av[4][2], b01[2][2], b23[2][2];

#pragma unroll
    for (int m = 0; m < 4; ++m) {
      av[m][0] = *(const bf16x8*)(aT + m * 1024 + xr0);
      av[m][1] = *(const bf16x8*)(aT + m * 1024 + xr1);
    }
#pragma unroll
    for (int n = 0; n < 2; ++n) {
      b01[n][0] = *(const bf16x8*)(bT + n * 1024 + xr0);
      b01[n][1] = *(const bf16x8*)(bT + n * 1024 + xr1);
    }
    if (tt + 1 < nkt) STG_A(0, tt + 1);
    __builtin_amdgcn_s_barrier();
    __builtin_amdgcn_s_setprio(1);
#pragma unroll
    for (int kk = 0; kk < 2; ++kk)
#pragma unroll
      for (int m = 0; m < 4; ++m)
#pragma unroll
        for (int n = 0; n < 2; ++n)
          acc[m][n] = __builtin_amdgcn_mfma_f32_16x16x32_bf16(
              av[m][kk], b01[n][kk], acc[m][n], 0, 0, 0);
    __builtin_amdgcn_s_setprio(0);
    __builtin_amdgcn_s_barrier();

#pragma unroll
    for (int n = 0; n < 2; ++n) {
      b23[n][0] = *(const bf16x8*)(bT + (2 + n) * 1024 + xr0);
      b23[n][1] = *(const bf16x8*)(bT + (2 + n) * 1024 + xr1);
    }
    if (tt + 1 < nkt) STG_A(1, tt + 1);
    __builtin_amdgcn_s_barrier();
    __builtin_amdgcn_s_setprio(1);
#pragma unroll
    for (int kk = 0; kk < 2; ++kk)
#pragma unroll
      for (int m = 0; m < 4; ++m)
#pragma unroll
        for (int n = 0; n < 2; ++n)
          acc[m][2 + n] = __builtin_amdgcn_mfma_f32_16x16x32_bf16(
              av[m][kk], b23[n][kk], acc[m][2 + n], 0, 0, 0);
    __builtin_amdgcn_s_setprio(0);
    __builtin_amdgcn_s_barrier();

#pragma unroll
    for (int m = 0; m < 4; ++m) {
      av[m][0] = *(const bf16x8*)(aT + (4 + m) * 1024 + xr0);
      av[m][1] = *(const bf16x8*)(aT + (4 + m) * 1024 + xr1);
    }
    if (tt + 2 < nkt) STG_B(0, tt + 2);
    __builtin_amdgcn_s_barrier();
    __builtin_amdgcn_s_setprio(1);
#pragma unroll
    for (int kk = 0; kk < 2; ++kk)
#pragma unroll
      for (int m = 0; m < 4; ++m)
#pragma unroll
        for (int n = 0; n < 2; ++n)
          acc[4 + m][2 + n] = __builtin_amdgcn_mfma_f32_16x16x32_bf16(
              av[m][kk], b23[n][kk], acc[4 + m][2 + n], 0, 0, 0);
    __builtin_amdgcn_s_setprio(0);
    __builtin_amdgcn_s_barrier();

    if (tt + 2 < nkt) STG_B(1, tt + 2);
    if (tt < nkt - 2) asm volatile("s_waitcnt vmcnt(4)" ::: "memory");
    else              asm volatile("s_waitcnt vmcnt(0)" ::: "memory");
    __builtin_amdgcn_sched_barrier(0);
    __builtin_amdgcn_s_barrier();
    __builtin_amdgcn_s_setprio(1);
#pragma unroll
    for (int kk = 0; kk < 2; ++kk)
#pragma unroll
      for (int m = 0; m < 4; ++m)
#pragma unroll
        for (int n = 0; n < 2; ++n)
          acc[4 + m][n] = __builtin_amdgcn_mfma_f32_16x16x32_bf16(
              av[m][kk], b01[n][kk], acc[4 + m][n], 0, 0, 0);
    __builtin_amdgcn_s_setprio(0);
    __builtin_amdgcn_s_barrier();
  }
#undef STG_A
#undef STG_B

#pragma unroll
  for (int mi = 0; mi < 8; ++mi)
#pragma unroll
    for (int nj = 0; nj < 4; ++nj) {
      int row = m0 + wm * 128 + mi * 16 + g * 4;
      int col = n0 + wn * 64 + nj * 16 + c;
      float sc = (SCALEQ && col < 4096) ? QSCALE : 1.0f;
#pragma unroll
      for (int r = 0; r < 4; ++r) {
        float x = acc[mi][nj][r] * sc;
        if (CBF16) ((u16*)C)[(size_t)(row + r) * N + col] = f2bf(x);
        else       ((float*)C)[(size_t)(row + r) * N + col] = x;
      }
    }
}

// ---------------- flash attention v3: 4 waves x QBLK=32 ----------------
// K/V fragment reads and barriers amortized over two 16-row halves (qb).
// LDS 80 KB -> 2 blocks/CU. Same swizzles/staging invariants as v2
// (row%16 of every staged K-row == w*4+g; V d%8 == lane>>3 pattern).
__global__ __launch_bounds__(256, 2) void attn_fwd3(
    const u16* __restrict__ qkv, const u16* __restrict__ vtg,
    u16* __restrict__ out) {
  __shared__ u16 Ks[2][64 * 128];      // [key][d-chunk ^ (key&15)]
  __shared__ u16 Vs[2][128 * 64];      // [d][key-chunk ^ (d&7)]
  __shared__ u16 Ps[4][32 * 64];       // per-wave [q][key-chunk16 ^ (q&7)]
  const int t = threadIdx.x;
  const int w = t >> 6, lane = t & 63;
  const int g = lane >> 4, c = lane & 15;
  const int bh = blockIdx.y;
  const int b = bh >> 5, h = bh & 31, kvh = h >> 2;
  const int q0 = blockIdx.x * 128 + w * 32;

  bf16x8 qf[2][4];
#pragma unroll
  for (int qb = 0; qb < 2; ++qb)
#pragma unroll
    for (int kk = 0; kk < 4; ++kk)
      qf[qb][kk] = *(const bf16x8*)&qkv[(size_t)((q0 + qb * 16 + c) * 2 + b) * QKVC + h * 128 + kk * 32 + g * 8];

  const f32x4 fz = {0.f, 0.f, 0.f, 0.f};
  f32x4 acc[2][8];
#pragma unroll
  for (int qb = 0; qb < 2; ++qb)
#pragma unroll
    for (int db = 0; db < 8; ++db) acc[qb][db] = fz;
  float m_[2] = {-__builtin_inff(), -__builtin_inff()};
  float l_[2] = {0.f, 0.f};

  const int w4g = w * 4 + g;           // w in 0..3 -> w4g in 0..15
  const u16* pK = qkv + (size_t)b * QKVC + 4096 + kvh * 128 + (size_t)((c ^ w4g) & 15) * 8;
  const int vrow = w * 8 + (lane >> 3);
  const u16* pV = vtg + (size_t)(b * 8 + kvh) * 128 * SEQ + (size_t)((lane & 7) ^ ((lane >> 3) & 7)) * 8;

  // K instr (j,w): LDS rows (j*4+w)*4+g <- global key kv0 + j*16 + w4g
  // V instr (j,w): LDS d-rows (j*4+w)*8+(lane>>3) <- global d j*32 + vrow
  auto stage = [&](int bufi, int kv0) {
#pragma unroll
    for (int j = 0; j < 4; ++j)
      gload16(pK + (size_t)(kv0 + j * 16 + w4g) * (2 * QKVC), &Ks[bufi][(j * 4 + w) * 512]);
#pragma unroll
    for (int j = 0; j < 4; ++j)
      gload16(pV + (size_t)(j * 32 + vrow) * SEQ + kv0, &Vs[bufi][(j * 4 + w) * 512]);
  };

  stage(0, 0);
  int buf = 0;
  for (int kv0 = 0; kv0 < SEQ; kv0 += 64) {
    __syncthreads();                   // tile staged; prev reads done
    if (kv0 + 64 < SEQ) stage(buf ^ 1, kv0 + 64);

    // S^T = K * Q^T; K-frags read once, used by both qb halves
    f32x4 st[2][4];
    __builtin_amdgcn_s_setprio(1);
#pragma unroll
    for (int kf = 0; kf < 4; ++kf) {
      const u16* kr = &Ks[buf][(kf * 16 + c) * 128];
      bf16x8 kfr[4];
#pragma unroll
      for (int kk = 0; kk < 4; ++kk)
        kfr[kk] = *(const bf16x8*)&kr[(((kk * 4 + g) ^ c) & 15) * 8];
#pragma unroll
      for (int qb = 0; qb < 2; ++qb) {
        f32x4 s = fz;
#pragma unroll
        for (int kk = 0; kk < 4; ++kk)
          s = __builtin_amdgcn_mfma_f32_16x16x32_bf16(kfr[kk], qf[qb][kk], s, 0, 0, 0);
        st[qb][kf] = s;
      }
    }
    __builtin_amdgcn_s_setprio(0);

    // online softmax per qb (stats at q = qb*16 + c)
#pragma unroll
    for (int qb = 0; qb < 2; ++qb) {
      float mloc = st[qb][0][0];
#pragma unroll
      for (int kf = 0; kf < 4; ++kf)
#pragma unroll
        for (int r = 0; r < 4; ++r) mloc = fmaxf(mloc, st[qb][kf][r]);
      mloc = fmaxf(mloc, __shfl_xor(mloc, 16));
      mloc = fmaxf(mloc, __shfl_xor(mloc, 32));
      if (!__all(mloc - m_[qb] <= 8.0f)) {
        float mnew = fmaxf(m_[qb], mloc);
        float alpha = __builtin_amdgcn_exp2f(m_[qb] - mnew);
        l_[qb] *= alpha;
        f32x4 av;
#pragma unroll
        for (int r = 0; r < 4; ++r) av[r] = __shfl(alpha, g * 4 + r);
#pragma unroll
        for (int db = 0; db < 8; ++db) acc[qb][db] *= av;
        m_[qb] = mnew;
      }
      float ps = 0.f;
#pragma unroll
      for (int kf = 0; kf < 4; ++kf) {
        u16x4 pk;
#pragma unroll
        for (int r = 0; r < 4; ++r) {
          float p = __builtin_amdgcn_exp2f(st[qb][kf][r] - m_[qb]);
          ps += p;
          pk[r] = f2bf(p);
        }
        int prow = qb * 16 + c;        // prow&7 == c&7
        *(u16x4*)&Ps[w][prow * 64 + ((((kf * 2 + (g >> 1)) ^ (c & 7)) << 3) | ((g & 1) << 2))] = pk;
      }
      ps += __shfl_xor(ps, 16);
      ps += __shfl_xor(ps, 32);
      l_[qb] += ps;
    }

    // PV: V-frags read once per db, used by both qb
    bf16x8 pa[2][2];
#pragma unroll
    for (int qb = 0; qb < 2; ++qb) {
      int prow = qb * 16 + c;
      pa[qb][0] = *(const bf16x8*)&Ps[w][prow * 64 + (((0 + g) ^ (c & 7)) << 3)];
      pa[qb][1] = *(const bf16x8*)&Ps[w][prow * 64 + (((4 + g) ^ (c & 7)) << 3)];
    }
    __builtin_amdgcn_s_setprio(1);
#pragma unroll
    for (int db = 0; db < 8; ++db) {
      const u16* vr = &Vs[buf][(db * 16 + c) * 64];
      bf16x8 v0 = *(const bf16x8*)&vr[(((0 + g) ^ (c & 7)) << 3)];
      bf16x8 v1 = *(const bf16x8*)&vr[(((4 + g) ^ (c & 7)) << 3)];
#pragma unroll
      for (int qb = 0; qb < 2; ++qb) {
        acc[qb][db] = __builtin_amdgcn_mfma_f32_16x16x32_bf16(pa[qb][0], v0, acc[qb][db], 0, 0, 0);
        acc[qb][db] = __builtin_amdgcn_mfma_f32_16x16x32_bf16(pa[qb][1], v1, acc[qb][db], 0, 0, 0);
      }
    }
    __builtin_amdgcn_s_setprio(0);
    buf ^= 1;
  }

#pragma unroll
  for (int qb = 0; qb < 2; ++qb) {
    float linv = __builtin_amdgcn_rcpf(l_[qb]);
    f32x4 il;
#pragma unroll
    for (int r = 0; r < 4; ++r) il[r] = __shfl(linv, g * 4 + r);
#pragma unroll
    for (int db = 0; db < 8; ++db) {
#pragma unroll
      for (int r = 0; r < 4; ++r) {
        int s = q0 + qb * 16 + g * 4 + r;
        out[(size_t)(s * 2 + b) * DM + h * 128 + db * 16 + c] = f2bf(acc[qb][db][r] * il[r]);
      }
    }
  }
}

// ---------------------------------------------------------------------------
extern "C" void kernel_launch(void* const* d_in, const int* in_sizes, int n_in,
                              void* d_out, int out_size, void* d_ws, size_t ws_size,
                              hipStream_t stream) {
  const float* hidden = (const float*)d_in[0];
  const float* w_qkv  = (const float*)d_in[1];
  const float* w_o    = (const float*)d_in[2];
  float* outp = (float*)d_out;

  const size_t SZ_X  = (size_t)NROWS * DM * 2;     // 32 MB
  const size_t SZ_WQ = (size_t)QKVC * DM * 2;      // 48 MB
  const size_t SZ_WO = (size_t)DM * DM * 2;        // 32 MB
  const size_t SZ_QKV = (size_t)NROWS * QKVC * 2;  // 48 MB
  if (ws_size < SZ_X + SZ_WQ + SZ_WO + SZ_QKV) return;  // 160 MB

  char* ws = (char*)d_ws;
  u16* Xb    = (u16*)ws;
  u16* WqkvT = (u16*)(ws + SZ_X);
  u16* WoT   = (u16*)(ws + SZ_X + SZ_WQ);
  u16* QKVb  = (u16*)(ws + SZ_X + SZ_WQ + SZ_WO);
  u16* VtG   = WqkvT;  // reuse: WqkvT dead after GEMM1 (V^T is 8 MB < 48 MB)
  u16* Attn  = Xb;     // reuse: Xb dead after GEMM1

  conv_f32_bf16<<<(NROWS * (size_t)DM) / 2048, 256, 0, stream>>>(hidden, Xb);
  transpose_f32_bf16<<<dim3(QKVC / 64, DM / 64), 256, 0, stream>>>(w_qkv, WqkvT, DM, QKVC);
  transpose_f32_bf16<<<dim3(DM / 64, DM / 64), 256, 0, stream>>>(w_o, WoT, DM, DM);
  // qkv = X @ Wqkv (q pre-scaled); 128x192 tiles -> 32*32 = 1024 blocks
  gemm128<1, 1><<<1024, 512, 0, stream>>>(Xb, WqkvT, QKVb, NROWS, QKVC, DM, 32);
  // V -> V^T
  vtrans<<<dim3(SEQ / 64, 2, 16), 256, 0, stream>>>(QKVb, VtG);
  // attention (4 waves x 32 q-rows; grid 16 x 64 = 1024 blocks, 2/CU)
  attn_fwd3<<<dim3(SEQ / 128, BATCH * 32), 256, 0, stream>>>(QKVb, VtG, Attn);
  // out = attn @ w_o (fp32); 256x256 tiles -> 256 blocks (1 perfect round)
  gemm256<0, 0><<<256, 512, 0, stream>>>(Attn, WoT, outp, NROWS, DM, DM, 16);
}

// Round 15
// 531.310 us; speedup vs baseline: 1.0073x; 1.0073x over previous
//
#include <hip/hip_runtime.h>
#include <hip/hip_bf16.h>

// ---------------------------------------------------------------------------
// ParallelLlamaRingAttention on MI355X (gfx950)  — r12 proven configuration
//   hidden[S=2048,B=2,4096] @ w_qkv[4096,6144] -> qkv
//   full (non-causal) GQA flash attention (NH=32, NKV=8, HD=128)
//   attn[4096,4096] @ w_o[4096,4096] -> out (fp32)
// GEMM1: 128x192 tile BK=64, 80 KB LDS -> 2 blocks/CU (4 waves/SIMD),
//        1024 blocks, simple {stage; vmcnt(5); bar; reads+MFMA; bar} loop.
// GEMM2: 256x256 BK=64 (256 blocks = 1 round), 4-phase, counted vmcnt(4).
// ATTN:  8 waves x QBLK=16, double-buffered K/Vt, exp2 softmax, defer-max.
// Both GEMMs: XOR-swizzled LDS + global_load_lds + setprio + XCD swizzle.
// ---------------------------------------------------------------------------

typedef __bf16 bf16x8 __attribute__((ext_vector_type(8)));
typedef float f32x4 __attribute__((ext_vector_type(4)));
typedef unsigned short u16;
typedef u16 u16x4 __attribute__((ext_vector_type(4)));
typedef u16 u16x8 __attribute__((ext_vector_type(8)));
typedef unsigned int u32;

#define SEQ    2048
#define BATCH  2
#define NROWS  4096      // S*B
#define DM     4096
#define QKVC   6144      // (32+16)*128
// log2e / sqrt(HD): softmax runs in exp2 domain
#define QSCALE (0.08838834764831845f * 1.4426950408889634f)

__device__ __forceinline__ u16 f2bf(float f) {
  union { float f; u32 u; } v; v.f = f;
  u32 r = v.u + 0x7fffu + ((v.u >> 16) & 1u);   // RNE
  return (u16)(r >> 16);
}

__device__ __forceinline__ void gload16(const void* g, void* l) {
  __builtin_amdgcn_global_load_lds(
      (const __attribute__((address_space(1))) unsigned int*)g,
      (__attribute__((address_space(3))) unsigned int*)l, 16, 0, 0);
}

// ---------------- fp32 -> bf16 elementwise ----------------
__global__ __launch_bounds__(256) void conv_f32_bf16(
    const float* __restrict__ in, u16* __restrict__ out) {
  size_t i = ((size_t)blockIdx.x * 256 + threadIdx.x) * 8;
  float4 a = *(const float4*)(in + i);
  float4 b = *(const float4*)(in + i + 4);
  u16x8 o;
  o[0] = f2bf(a.x); o[1] = f2bf(a.y); o[2] = f2bf(a.z); o[3] = f2bf(a.w);
  o[4] = f2bf(b.x); o[5] = f2bf(b.y); o[6] = f2bf(b.z); o[7] = f2bf(b.w);
  *(u16x8*)(out + i) = o;
}

// ---------------- fp32 [K][N] -> bf16 [N][K] transpose ----------------
__global__ __launch_bounds__(256) void transpose_f32_bf16(
    const float* __restrict__ in, u16* __restrict__ out, int K, int N) {
  __shared__ u16 tile[64][65];
  const int k0 = blockIdx.y * 64, n0 = blockIdx.x * 64;
  const int t = threadIdx.x;
#pragma unroll
  for (int i = 0; i < 4; ++i) {
    int slot = i * 256 + t;
    int r = slot >> 4, cq = slot & 15;
    float4 v = *(const float4*)(in + (size_t)(k0 + r) * N + n0 + cq * 4);
    tile[cq * 4 + 0][r] = f2bf(v.x);
    tile[cq * 4 + 1][r] = f2bf(v.y);
    tile[cq * 4 + 2][r] = f2bf(v.z);
    tile[cq * 4 + 3][r] = f2bf(v.w);
  }
  __syncthreads();
#pragma unroll
  for (int i = 0; i < 2; ++i) {
    int slot = i * 256 + t;
    int n = slot >> 3, q = slot & 7;
    u16x8 o;
#pragma unroll
    for (int e = 0; e < 8; ++e) o[e] = tile[n][q * 8 + e];
    *(u16x8*)(out + (size_t)(n0 + n) * K + k0 + q * 8) = o;
  }
}

// ---------------- bf16 V [s][b][kvh][d] -> Vt [(b*8+kvh)*128+d][s] ----------
__global__ __launch_bounds__(256) void vtrans(
    const u16* __restrict__ qkv, u16* __restrict__ vt) {
  __shared__ u16 tile[64][66];
  const int s0 = blockIdx.x * 64, d0 = blockIdx.y * 64;
  const int z = blockIdx.z;            // b*8+kvh
  const int b = z >> 3, kvh = z & 7;
  const int t = threadIdx.x;
#pragma unroll
  for (int i = 0; i < 2; ++i) {
    int chunk = i * 256 + t;
    int r = chunk >> 3, q = chunk & 7;
    u16x8 v = *(const u16x8*)&qkv[(size_t)((s0 + r) * 2 + b) * QKVC + 5120 + kvh * 128 + d0 + q * 8];
#pragma unroll
    for (int e = 0; e < 8; ++e) tile[r][q * 8 + e] = v[e];
  }
  __syncthreads();
#pragma unroll
  for (int i = 0; i < 2; ++i) {
    int chunk = i * 256 + t;
    int d = chunk >> 3, q = chunk & 7;
    u16x8 o;
#pragma unroll
    for (int e = 0; e < 8; ++e) o[e] = tile[q * 8 + e][d];
    *(u16x8*)&vt[(size_t)(z * 128 + d0 + d) * SEQ + s0 + q * 8] = o;
  }
}

// ---------------- bf16 GEMM 128x192: C = A[M,K] * B^T[N,K] ------------------
// 8 waves (2M x 4N), per-wave 64x48, BK=64. LDS 80 KB -> 2 blocks/CU.
// Per tile: {stage(t+1)->alt buf; vmcnt(5) confirms t (t+1 stays flying);
// barrier; 14 ds_read_b128 + 24 MFMA (compiler lgkm-interleaved); barrier}.
template <int CBF16, int SCALEQ>
__global__ __launch_bounds__(512, 4) void gemm128(
    const u16* __restrict__ A, const u16* __restrict__ B,
    void* __restrict__ C, int M, int N, int K, int nby) {
  __shared__ u16 As[2 * 8192];    // [2][128][64] 32 KB
  __shared__ u16 Bs[2 * 12288];   // [2][192][64] 48 KB
  const int t = threadIdx.x;
  const int w = t >> 6, l = t & 63;
  const int g = l >> 4, c = l & 15;
  const int wm = w >> 2, wn = w & 3;

  // bijective XCD swizzle (1024 % 8 == 0); consecutive sid share bx
  const int nwg = gridDim.x;
  const int sid = (blockIdx.x & 7) * (nwg >> 3) + (blockIdx.x >> 3);
  const int by = sid % nby, bx = sid / nby;
  const int m0 = by * 128, n0 = bx * 192;

  const int gsrc = (l & 7) ^ (l >> 3);
  const u16* pA = A + (size_t)(m0 + w * 8 + (l >> 3)) * K + gsrc * 8;
  const u16* pB = B + (size_t)(n0 + w * 8 + (l >> 3)) * K + gsrc * 8;

#define STG128(tt) do { int d_ = (tt) & 1;                                  \
    _Pragma("unroll")                                                       \
    for (int u = 0; u < 2; ++u)                                             \
      gload16(pA + (size_t)(u * 64) * K + (size_t)(tt) * 64,                \
              &As[d_ * 8192 + u * 4096 + w * 512]);                         \
    _Pragma("unroll")                                                       \
    for (int u = 0; u < 3; ++u)                                             \
      gload16(pB + (size_t)(u * 64) * K + (size_t)(tt) * 64,                \
              &Bs[d_ * 12288 + u * 4096 + w * 512]); } while (0)

  const int xr0 = ((0 + g) ^ (c & 7)) << 3;
  const int xr1 = ((4 + g) ^ (c & 7)) << 3;

  const f32x4 fz = {0.f, 0.f, 0.f, 0.f};
  f32x4 acc[4][3];
#pragma unroll
  for (int m = 0; m < 4; ++m)
#pragma unroll
    for (int n = 0; n < 3; ++n) acc[m][n] = fz;

  const int nkt = K >> 6;
  STG128(0);
  for (int tt = 0; tt < nkt; ++tt) {
    const int d = tt & 1;
    if (tt + 1 < nkt) {
      STG128(tt + 1);
      asm volatile("s_waitcnt vmcnt(5)" ::: "memory");  // tile t confirmed
    } else {
      asm volatile("s_waitcnt vmcnt(0)" ::: "memory");
    }
    __builtin_amdgcn_sched_barrier(0);
    __builtin_amdgcn_s_barrier();                       // all-waves: t ready

    const u16* aT = &As[d * 8192 + (wm * 64 + c) * 64];
    const u16* bT = &Bs[d * 12288 + (wn * 48 + c) * 64];
    bf16x8 av[4][2], bv[3][2];
#pragma unroll
    for (int m = 0; m < 4; ++m) {
      av[m][0] = *(const bf16x8*)(aT + m * 1024 + xr0);
      av[m][1] = *(const bf16x8*)(aT + m * 1024 + xr1);
    }
#pragma unroll
    for (int n = 0; n < 3; ++n) {
      bv[n][0] = *(const bf16x8*)(bT + n * 1024 + xr0);
      bv[n][1] = *(const bf16x8*)(bT + n * 1024 + xr1);
    }
    __builtin_amdgcn_s_setprio(1);
#pragma unroll
    for (int kk = 0; kk < 2; ++kk)
#pragma unroll
      for (int m = 0; m < 4; ++m)
#pragma unroll
        for (int n = 0; n < 3; ++n)
          acc[m][n] = __builtin_amdgcn_mfma_f32_16x16x32_bf16(
              av[m][kk], bv[n][kk], acc[m][n], 0, 0, 0);
    __builtin_amdgcn_s_setprio(0);
    __builtin_amdgcn_s_barrier();                       // reads of buf d done
  }
#undef STG128

#pragma unroll
  for (int m = 0; m < 4; ++m)
#pragma unroll
    for (int n = 0; n < 3; ++n) {
      int row = m0 + wm * 64 + m * 16 + g * 4;
      int col = n0 + wn * 48 + n * 16 + c;
      float sc = (SCALEQ && col < 4096) ? QSCALE : 1.0f;
#pragma unroll
      for (int r = 0; r < 4; ++r) {
        float x = acc[m][n][r] * sc;
        if (CBF16) ((u16*)C)[(size_t)(row + r) * N + col] = f2bf(x);
        else       ((float*)C)[(size_t)(row + r) * N + col] = x;
      }
    }
}

// ---------------- bf16 GEMM 256x256 (4-phase, unpinned barriers) ------------
template <int CBF16, int SCALEQ>
__global__ __launch_bounds__(512, 2) void gemm256(
    const u16* __restrict__ A, const u16* __restrict__ B,
    void* __restrict__ C, int M, int N, int K, int nby) {
  __shared__ u16 As[2 * 2 * 8192];   // 64 KB
  __shared__ u16 Bs[2 * 2 * 8192];   // 64 KB
  const int t = threadIdx.x;
  const int w = t >> 6, l = t & 63;
  const int g = l >> 4, c = l & 15;
  const int wm = w >> 2, wn = w & 3;

  const int nwg = gridDim.x;
  const int sid = (blockIdx.x & 7) * (nwg >> 3) + (blockIdx.x >> 3);
  const int by = sid % nby, bx = sid / nby;
  const int m0 = by * 256, n0 = bx * 256;

  const int gsrc = (l & 7) ^ (l >> 3);
  const u16* pA = A + (size_t)(m0 + w * 8 + (l >> 3)) * K + gsrc * 8;
  const u16* pB = B + (size_t)(n0 + w * 8 + (l >> 3)) * K + gsrc * 8;

#define STG_A(h, tt) do { int d_ = (tt) & 1;                                    \
    gload16(pA + (size_t)((h) * 128) * K + (tt) * 64,                           \
            &As[(d_ * 2 + (h)) * 8192 + w * 512]);                              \
    gload16(pA + (size_t)((h) * 128 + 64) * K + (tt) * 64,                      \
            &As[(d_ * 2 + (h)) * 8192 + 4096 + w * 512]); } while (0)
#define STG_B(h, tt) do { int d_ = (tt) & 1;                                    \
    gload16(pB + (size_t)((h) * 128) * K + (tt) * 64,                           \
            &Bs[(d_ * 2 + (h)) * 8192 + w * 512]);                              \
    gload16(pB + (size_t)((h) * 128 + 64) * K + (tt) * 64,                      \
            &Bs[(d_ * 2 + (h)) * 8192 + 4096 + w * 512]); } while (0)

  const u16* aRd = &As[wm * 8192 + c * 64];
  const u16* bRd = &Bs[(wn >> 1) * 8192 + ((wn & 1) * 64 + c) * 64];
  const int xr0 = ((0 + g) ^ (c & 7)) << 3;
  const int xr1 = ((4 + g) ^ (c & 7)) << 3;

  const f32x4 fz = {0.f, 0.f, 0.f, 0.f};
  f32x4 acc[8][4];
#pragma unroll
  for (int mi = 0; mi < 8; ++mi)
#pragma unroll
    for (int nj = 0; nj < 4; ++nj) acc[mi][nj] = fz;

  const int nkt = K >> 6;
  STG_A(0, 0); STG_A(1, 0); STG_B(0, 0); STG_B(1, 0);
  STG_B(0, 1); STG_B(1, 1);
  asm volatile("s_waitcnt vmcnt(4)" ::: "memory");
  __builtin_amdgcn_sched_barrier(0);
  __builtin_amdgcn_s_barrier();

  for (int tt = 0; tt < nkt; ++tt) {
    const int d = tt & 1;
    const u16* aT = aRd + d * 16384;
    const u16* bT = bRd + d * 16384;
    bf16x8 av[4][2], b01[2][2], b23[2][2];

    // ---- P0: A-lo + B01; stage A0(t+1)
#pragma unroll
    for (int m = 0; m < 4; ++m) {
      av[m][0] = *(const bf16x8*)(aT + m * 1024 + xr0);
      av[m][1] = *(const bf16x8*)(aT + m * 1024 + xr1);
    }
#pragma unroll
    for (int n = 0; n < 2; ++n) {
      b01[n][0] = *(const bf16x8*)(bT + n * 1024 + xr0);
      b01[n][1] = *(const bf16x8*)(bT + n * 1024 + xr1);
    }
    if (tt + 1 < nkt) STG_A(0, tt + 1);
    __builtin_amdgcn_s_barrier();
    __builtin_amdgcn_s_setprio(1);
#pragma unroll
    for (int kk = 0; kk < 2; ++kk)
#pragma unroll
      for (int m = 0; m < 4; ++m)
#pragma unroll
        for (int n = 0; n < 2; ++n)
          acc[m][n] = __builtin_amdgcn_mfma_f32_16x16x32_bf16(
              av[m][kk], b01[n][kk], acc[m][n], 0, 0, 0);
    __builtin_amdgcn_s_setprio(0);
    __builtin_amdgcn_s_barrier();

    // ---- P1: B23; stage A1(t+1)
#pragma unroll
    for (int n = 0; n < 2; ++n) {
      b23[n][0] = *(const bf16x8*)(bT + (2 + n) * 1024 + xr0);
      b23[n][1] = *(const bf16x8*)(bT + (2 + n) * 1024 + xr1);
    }
    if (tt + 1 < nkt) STG_A(1, tt + 1);
    __builtin_amdgcn_s_barrier();
    __builtin_amdgcn_s_setprio(1);
#pragma unroll
    for (int kk = 0; kk < 2; ++kk)
#pragma unroll
      for (int m = 0; m < 4; ++m)
#pragma unroll
        for (int n = 0; n < 2; ++n)
          acc[m][2 + n] = __builtin_amdgcn_mfma_f32_16x16x32_bf16(
              av[m][kk], b23[n][kk], acc[m][2 + n], 0, 0, 0);
    __builtin_amdgcn_s_setprio(0);
    __builtin_amdgcn_s_barrier();

    // ---- P2: A-hi; stage B0(t+2)
#pragma unroll
    for (int m = 0; m < 4; ++m) {
      av[m][0] = *(const bf16x8*)(aT + (4 + m) * 1024 + xr0);
      av[m][1] = *(const bf16x8*)(aT + (4 + m) * 1024 + xr1);
    }
    if (tt + 2 < nkt) STG_B(0, tt + 2);
    __builtin_amdgcn_s_barrier();
    __builtin_amdgcn_s_setprio(1);
#pragma unroll
    for (int kk = 0; kk < 2; ++kk)
#pragma unroll
      for (int m = 0; m < 4; ++m)
#pragma unroll
        for (int n = 0; n < 2; ++n)
          acc[4 + m][2 + n] = __builtin_amdgcn_mfma_f32_16x16x32_bf16(
              av[m][kk], b23[n][kk], acc[4 + m][2 + n], 0, 0, 0);
    __builtin_amdgcn_s_setprio(0);
    __builtin_amdgcn_s_barrier();

    // ---- P3: stage B1(t+2); counted vmcnt
    if (tt + 2 < nkt) STG_B(1, tt + 2);
    if (tt < nkt - 2) asm volatile("s_waitcnt vmcnt(4)" ::: "memory");
    else              asm volatile("s_waitcnt vmcnt(0)" ::: "memory");
    __builtin_amdgcn_sched_barrier(0);
    __builtin_amdgcn_s_barrier();
    __builtin_amdgcn_s_setprio(1);
#pragma unroll
    for (int kk = 0; kk < 2; ++kk)
#pragma unroll
      for (int m = 0; m < 4; ++m)
#pragma unroll
        for (int n = 0; n < 2; ++n)
          acc[4 + m][n] = __builtin_amdgcn_mfma_f32_16x16x32_bf16(
              av[m][kk], b01[n][kk], acc[4 + m][n], 0, 0, 0);
    __builtin_amdgcn_s_setprio(0);
    __builtin_amdgcn_s_barrier();
  }
#undef STG_A
#undef STG_B

#pragma unroll
  for (int mi = 0; mi < 8; ++mi)
#pragma unroll
    for (int nj = 0; nj < 4; ++nj) {
      int row = m0 + wm * 128 + mi * 16 + g * 4;
      int col = n0 + wn * 64 + nj * 16 + c;
      float sc = (SCALEQ && col < 4096) ? QSCALE : 1.0f;
#pragma unroll
      for (int r = 0; r < 4; ++r) {
        float x = acc[mi][nj][r] * sc;
        if (CBF16) ((u16*)C)[(size_t)(row + r) * N + col] = f2bf(x);
        else       ((float*)C)[(size_t)(row + r) * N + col] = x;
      }
    }
}

// ---------------- flash attention v2 (full, GQA) ----------------
__global__ __launch_bounds__(512, 4) void attn_fwd2(
    const u16* __restrict__ qkv, const u16* __restrict__ vtg,
    u16* __restrict__ out) {
  __shared__ u16 Ks[2][64 * 128];      // [key][d-chunk ^ (key&15)]
  __shared__ u16 Vs[2][128 * 64];      // [d][key-chunk ^ (d&7)]
  __shared__ u16 Ps[8][16 * 64];       // per-wave [q][key-chunk16 ^ (q&7)]
  const int t = threadIdx.x;
  const int w = t >> 6, lane = t & 63;
  const int g = lane >> 4, c = lane & 15;
  const int bh = blockIdx.y;
  const int b = bh >> 5, h = bh & 31, kvh = h >> 2;
  const int q0 = blockIdx.x * 128 + w * 16;

  bf16x8 qf[4];
#pragma unroll
  for (int kk = 0; kk < 4; ++kk)
    qf[kk] = *(const bf16x8*)&qkv[(size_t)((q0 + c) * 2 + b) * QKVC + h * 128 + kk * 32 + g * 8];

  const f32x4 fz = {0.f, 0.f, 0.f, 0.f};
  f32x4 acc[8];
#pragma unroll
  for (int db = 0; db < 8; ++db) acc[db] = fz;
  float m_ = -__builtin_inff(), l_ = 0.f;

  const int w4g = w * 4 + g;
  const u16* pK = qkv + (size_t)b * QKVC + 4096 + kvh * 128 + (size_t)((c ^ w4g) & 15) * 8;
  const int vrow = w * 8 + (lane >> 3);
  const u16* pV = vtg + (size_t)(b * 8 + kvh) * 128 * SEQ + (size_t)((lane & 7) ^ (lane >> 3)) * 8;

  auto stage = [&](int bufi, int kv0) {
#pragma unroll
    for (int j = 0; j < 2; ++j)
      gload16(pK + (size_t)(kv0 + j * 32 + w4g) * (2 * QKVC), &Ks[bufi][(j * 8 + w) * 512]);
#pragma unroll
    for (int j = 0; j < 2; ++j)
      gload16(pV + (size_t)(j * 64 + vrow) * SEQ + kv0, &Vs[bufi][(j * 8 + w) * 512]);
  };

  stage(0, 0);
  int buf = 0;
  for (int kv0 = 0; kv0 < SEQ; kv0 += 64) {
    __syncthreads();
    if (kv0 + 64 < SEQ) stage(buf ^ 1, kv0 + 64);

    f32x4 st[4];
    __builtin_amdgcn_s_setprio(1);
#pragma unroll
    for (int kf = 0; kf < 4; ++kf) {
      const u16* kr = &Ks[buf][(kf * 16 + c) * 128];
      bf16x8 kfr[4];
#pragma unroll
      for (int kk = 0; kk < 4; ++kk)
        kfr[kk] = *(const bf16x8*)&kr[(((kk * 4 + g) ^ c) & 15) * 8];
      f32x4 s = fz;
#pragma unroll
      for (int kk = 0; kk < 4; ++kk)
        s = __builtin_amdgcn_mfma_f32_16x16x32_bf16(kfr[kk], qf[kk], s, 0, 0, 0);
      st[kf] = s;
    }
    __builtin_amdgcn_s_setprio(0);

    float mloc = st[0][0];
#pragma unroll
    for (int kf = 0; kf < 4; ++kf)
#pragma unroll
      for (int r = 0; r < 4; ++r) mloc = fmaxf(mloc, st[kf][r]);
    mloc = fmaxf(mloc, __shfl_xor(mloc, 16));
    mloc = fmaxf(mloc, __shfl_xor(mloc, 32));
    if (!__all(mloc - m_ <= 8.0f)) {
      float mnew = fmaxf(m_, mloc);
      float alpha = __builtin_amdgcn_exp2f(m_ - mnew);
      l_ *= alpha;
      f32x4 av;
#pragma unroll
      for (int r = 0; r < 4; ++r) av[r] = __shfl(alpha, g * 4 + r);
#pragma unroll
      for (int db = 0; db < 8; ++db) acc[db] *= av;
      m_ = mnew;
    }
    float ps = 0.f;
#pragma unroll
    for (int kf = 0; kf < 4; ++kf) {
      u16x4 pk;
#pragma unroll
      for (int r = 0; r < 4; ++r) {
        float p = __builtin_amdgcn_exp2f(st[kf][r] - m_);
        ps += p;
        pk[r] = f2bf(p);
      }
      *(u16x4*)&Ps[w][c * 64 + ((((kf * 2 + (g >> 1)) ^ (c & 7)) << 3) | ((g & 1) << 2))] = pk;
    }
    ps += __shfl_xor(ps, 16);
    ps += __shfl_xor(ps, 32);
    l_ += ps;

    bf16x8 pa0 = *(const bf16x8*)&Ps[w][c * 64 + (((0 + g) ^ (c & 7)) << 3)];
    bf16x8 pa1 = *(const bf16x8*)&Ps[w][c * 64 + (((4 + g) ^ (c & 7)) << 3)];
    __builtin_amdgcn_s_setprio(1);
#pragma unroll
    for (int db = 0; db < 8; ++db) {
      const u16* vr = &Vs[buf][(db * 16 + c) * 64];
      bf16x8 v0 = *(const bf16x8*)&vr[(((0 + g) ^ (c & 7)) << 3)];
      bf16x8 v1 = *(const bf16x8*)&vr[(((4 + g) ^ (c & 7)) << 3)];
      acc[db] = __builtin_amdgcn_mfma_f32_16x16x32_bf16(pa0, v0, acc[db], 0, 0, 0);
      acc[db] = __builtin_amdgcn_mfma_f32_16x16x32_bf16(pa1, v1, acc[db], 0, 0, 0);
    }
    __builtin_amdgcn_s_setprio(0);
    buf ^= 1;
  }

  float linv = __builtin_amdgcn_rcpf(l_);
  f32x4 il;
#pragma unroll
  for (int r = 0; r < 4; ++r) il[r] = __shfl(linv, g * 4 + r);
#pragma unroll
  for (int db = 0; db < 8; ++db) {
#pragma unroll
    for (int r = 0; r < 4; ++r) {
      int s = q0 + g * 4 + r;
      out[(size_t)(s * 2 + b) * DM + h * 128 + db * 16 + c] = f2bf(acc[db][r] * il[r]);
    }
  }
}

// ---------------------------------------------------------------------------
extern "C" void kernel_launch(void* const* d_in, const int* in_sizes, int n_in,
                              void* d_out, int out_size, void* d_ws, size_t ws_size,
                              hipStream_t stream) {
  const float* hidden = (const float*)d_in[0];
  const float* w_qkv  = (const float*)d_in[1];
  const float* w_o    = (const float*)d_in[2];
  float* outp = (float*)d_out;

  const size_t SZ_X  = (size_t)NROWS * DM * 2;     // 32 MB
  const size_t SZ_WQ = (size_t)QKVC * DM * 2;      // 48 MB
  const size_t SZ_WO = (size_t)DM * DM * 2;        // 32 MB
  const size_t SZ_QKV = (size_t)NROWS * QKVC * 2;  // 48 MB
  if (ws_size < SZ_X + SZ_WQ + SZ_WO + SZ_QKV) return;  // 160 MB

  char* ws = (char*)d_ws;
  u16* Xb    = (u16*)ws;
  u16* WqkvT = (u16*)(ws + SZ_X);
  u16* WoT   = (u16*)(ws + SZ_X + SZ_WQ);
  u16* QKVb  = (u16*)(ws + SZ_X + SZ_WQ + SZ_WO);
  u16* VtG   = WqkvT;  // reuse: WqkvT dead after GEMM1 (V^T is 8 MB < 48 MB)
  u16* Attn  = Xb;     // reuse: Xb dead after GEMM1

  conv_f32_bf16<<<(NROWS * (size_t)DM) / 2048, 256, 0, stream>>>(hidden, Xb);
  transpose_f32_bf16<<<dim3(QKVC / 64, DM / 64), 256, 0, stream>>>(w_qkv, WqkvT, DM, QKVC);
  transpose_f32_bf16<<<dim3(DM / 64, DM / 64), 256, 0, stream>>>(w_o, WoT, DM, DM);
  // qkv = X @ Wqkv (q pre-scaled); 128x192 tiles -> 32*32 = 1024 blocks
  gemm128<1, 1><<<1024, 512, 0, stream>>>(Xb, WqkvT, QKVb, NROWS, QKVC, DM, 32);
  // V -> V^T
  vtrans<<<dim3(SEQ / 64, 2, 16), 256, 0, stream>>>(QKVb, VtG);
  // attention
  attn_fwd2<<<dim3(SEQ / 128, BATCH * 32), 512, 0, stream>>>(QKVb, VtG, Attn);
  // out = attn @ w_o (fp32); 256x256 tiles -> 256 blocks (1 perfect round)
  gemm256<0, 0><<<256, 512, 0, stream>>>(Attn, WoT, outp, NROWS, DM, DM, 16);
}

// Round 16
// 530.497 us; speedup vs baseline: 1.0089x; 1.0015x over previous
//
#include <hip/hip_runtime.h>
#include <hip/hip_bf16.h>

// ---------------------------------------------------------------------------
// ParallelLlamaRingAttention on MI355X (gfx950)
//   hidden[S=2048,B=2,4096] @ w_qkv[4096,6144] -> qkv
//   full (non-causal) GQA flash attention (NH=32, NKV=8, HD=128)
//   attn[4096,4096] @ w_o[4096,4096] -> out (fp32)
// GEMM1: 128x192 BK=64, 80 KB LDS -> 2 blocks/CU; 1024 blocks; per-XCD
//        2D rectangular chunk (16by x 8bx) for A+B L2 locality.
// GEMM2: 256x256 BK=64, 4-phase, counted vmcnt(4); per-XCD 8by x 4bx chunk.
// ATTN:  8 waves x QBLK=16, double-buffered K/Vt, exp2 softmax, defer-max.
// ---------------------------------------------------------------------------

typedef __bf16 bf16x8 __attribute__((ext_vector_type(8)));
typedef float f32x4 __attribute__((ext_vector_type(4)));
typedef unsigned short u16;
typedef u16 u16x4 __attribute__((ext_vector_type(4)));
typedef u16 u16x8 __attribute__((ext_vector_type(8)));
typedef unsigned int u32;

#define SEQ    2048
#define BATCH  2
#define NROWS  4096      // S*B
#define DM     4096
#define QKVC   6144      // (32+16)*128
// log2e / sqrt(HD): softmax runs in exp2 domain
#define QSCALE (0.08838834764831845f * 1.4426950408889634f)

__device__ __forceinline__ u16 f2bf(float f) {
  union { float f; u32 u; } v; v.f = f;
  u32 r = v.u + 0x7fffu + ((v.u >> 16) & 1u);   // RNE
  return (u16)(r >> 16);
}

__device__ __forceinline__ void gload16(const void* g, void* l) {
  __builtin_amdgcn_global_load_lds(
      (const __attribute__((address_space(1))) unsigned int*)g,
      (__attribute__((address_space(3))) unsigned int*)l, 16, 0, 0);
}

// ---------------- fp32 -> bf16 elementwise ----------------
__global__ __launch_bounds__(256) void conv_f32_bf16(
    const float* __restrict__ in, u16* __restrict__ out) {
  size_t i = ((size_t)blockIdx.x * 256 + threadIdx.x) * 8;
  float4 a = *(const float4*)(in + i);
  float4 b = *(const float4*)(in + i + 4);
  u16x8 o;
  o[0] = f2bf(a.x); o[1] = f2bf(a.y); o[2] = f2bf(a.z); o[3] = f2bf(a.w);
  o[4] = f2bf(b.x); o[5] = f2bf(b.y); o[6] = f2bf(b.z); o[7] = f2bf(b.w);
  *(u16x8*)(out + i) = o;
}

// ---------------- fp32 [K][N] -> bf16 [N][K] transpose ----------------
__global__ __launch_bounds__(256) void transpose_f32_bf16(
    const float* __restrict__ in, u16* __restrict__ out, int K, int N) {
  __shared__ u16 tile[64][65];
  const int k0 = blockIdx.y * 64, n0 = blockIdx.x * 64;
  const int t = threadIdx.x;
#pragma unroll
  for (int i = 0; i < 4; ++i) {
    int slot = i * 256 + t;
    int r = slot >> 4, cq = slot & 15;
    float4 v = *(const float4*)(in + (size_t)(k0 + r) * N + n0 + cq * 4);
    tile[cq * 4 + 0][r] = f2bf(v.x);
    tile[cq * 4 + 1][r] = f2bf(v.y);
    tile[cq * 4 + 2][r] = f2bf(v.z);
    tile[cq * 4 + 3][r] = f2bf(v.w);
  }
  __syncthreads();
#pragma unroll
  for (int i = 0; i < 2; ++i) {
    int slot = i * 256 + t;
    int n = slot >> 3, q = slot & 7;
    u16x8 o;
#pragma unroll
    for (int e = 0; e < 8; ++e) o[e] = tile[n][q * 8 + e];
    *(u16x8*)(out + (size_t)(n0 + n) * K + k0 + q * 8) = o;
  }
}

// ---------------- bf16 V [s][b][kvh][d] -> Vt [(b*8+kvh)*128+d][s] ----------
__global__ __launch_bounds__(256) void vtrans(
    const u16* __restrict__ qkv, u16* __restrict__ vt) {
  __shared__ u16 tile[64][66];
  const int s0 = blockIdx.x * 64, d0 = blockIdx.y * 64;
  const int z = blockIdx.z;            // b*8+kvh
  const int b = z >> 3, kvh = z & 7;
  const int t = threadIdx.x;
#pragma unroll
  for (int i = 0; i < 2; ++i) {
    int chunk = i * 256 + t;
    int r = chunk >> 3, q = chunk & 7;
    u16x8 v = *(const u16x8*)&qkv[(size_t)((s0 + r) * 2 + b) * QKVC + 5120 + kvh * 128 + d0 + q * 8];
#pragma unroll
    for (int e = 0; e < 8; ++e) tile[r][q * 8 + e] = v[e];
  }
  __syncthreads();
#pragma unroll
  for (int i = 0; i < 2; ++i) {
    int chunk = i * 256 + t;
    int d = chunk >> 3, q = chunk & 7;
    u16x8 o;
#pragma unroll
    for (int e = 0; e < 8; ++e) o[e] = tile[q * 8 + e][d];
    *(u16x8*)&vt[(size_t)(z * 128 + d0 + d) * SEQ + s0 + q * 8] = o;
  }
}

// ---------------- bf16 GEMM 128x192: C = A[M,K] * B^T[N,K] ------------------
// 8 waves (2M x 4N), per-wave 64x48, BK=64. LDS 80 KB -> 2 blocks/CU.
// Per tile: {stage(t+1)->alt buf; vmcnt(5) confirms t (t+1 stays flying);
// barrier; 14 ds_read_b128 + 24 MFMA (compiler lgkm-interleaved); barrier}.
// XCD chunking: grid 32by x 32bx; XCD k owns the 16by x 8bx rectangle
// (by base (k>>2)*16, bx base (k&3)*8) -> per-XCD unique fetch 28 MB.
template <int CBF16, int SCALEQ>
__global__ __launch_bounds__(512, 4) void gemm128(
    const u16* __restrict__ A, const u16* __restrict__ B,
    void* __restrict__ C, int M, int N, int K) {
  __shared__ u16 As[2 * 8192];    // [2][128][64] 32 KB
  __shared__ u16 Bs[2 * 12288];   // [2][192][64] 48 KB
  const int t = threadIdx.x;
  const int w = t >> 6, l = t & 63;
  const int g = l >> 4, c = l & 15;
  const int wm = w >> 2, wn = w & 3;

  // 2D-chunked bijective XCD mapping (1024 blocks, bid%8 = XCD)
  const int xcd = blockIdx.x & 7;
  const int idx = blockIdx.x >> 3;           // 0..127
  const int by = (xcd >> 2) * 16 + (idx >> 3);
  const int bx = (xcd & 3) * 8 + (idx & 7);
  const int m0 = by * 128, n0 = bx * 192;

  const int gsrc = (l & 7) ^ (l >> 3);
  const u16* pA = A + (size_t)(m0 + w * 8 + (l >> 3)) * K + gsrc * 8;
  const u16* pB = B + (size_t)(n0 + w * 8 + (l >> 3)) * K + gsrc * 8;

#define STG128(tt) do { int d_ = (tt) & 1;                                  \
    _Pragma("unroll")                                                       \
    for (int u = 0; u < 2; ++u)                                             \
      gload16(pA + (size_t)(u * 64) * K + (size_t)(tt) * 64,                \
              &As[d_ * 8192 + u * 4096 + w * 512]);                         \
    _Pragma("unroll")                                                       \
    for (int u = 0; u < 3; ++u)                                             \
      gload16(pB + (size_t)(u * 64) * K + (size_t)(tt) * 64,                \
              &Bs[d_ * 12288 + u * 4096 + w * 512]); } while (0)

  const int xr0 = ((0 + g) ^ (c & 7)) << 3;
  const int xr1 = ((4 + g) ^ (c & 7)) << 3;

  const f32x4 fz = {0.f, 0.f, 0.f, 0.f};
  f32x4 acc[4][3];
#pragma unroll
  for (int m = 0; m < 4; ++m)
#pragma unroll
    for (int n = 0; n < 3; ++n) acc[m][n] = fz;

  const int nkt = K >> 6;
  STG128(0);
  for (int tt = 0; tt < nkt; ++tt) {
    const int d = tt & 1;
    if (tt + 1 < nkt) {
      STG128(tt + 1);
      asm volatile("s_waitcnt vmcnt(5)" ::: "memory");  // tile t confirmed
    } else {
      asm volatile("s_waitcnt vmcnt(0)" ::: "memory");
    }
    __builtin_amdgcn_sched_barrier(0);
    __builtin_amdgcn_s_barrier();                       // all-waves: t ready

    const u16* aT = &As[d * 8192 + (wm * 64 + c) * 64];
    const u16* bT = &Bs[d * 12288 + (wn * 48 + c) * 64];
    bf16x8 av[4][2], bv[3][2];
#pragma unroll
    for (int m = 0; m < 4; ++m) {
      av[m][0] = *(const bf16x8*)(aT + m * 1024 + xr0);
      av[m][1] = *(const bf16x8*)(aT + m * 1024 + xr1);
    }
#pragma unroll
    for (int n = 0; n < 3; ++n) {
      bv[n][0] = *(const bf16x8*)(bT + n * 1024 + xr0);
      bv[n][1] = *(const bf16x8*)(bT + n * 1024 + xr1);
    }
    __builtin_amdgcn_s_setprio(1);
#pragma unroll
    for (int kk = 0; kk < 2; ++kk)
#pragma unroll
      for (int m = 0; m < 4; ++m)
#pragma unroll
        for (int n = 0; n < 3; ++n)
          acc[m][n] = __builtin_amdgcn_mfma_f32_16x16x32_bf16(
              av[m][kk], bv[n][kk], acc[m][n], 0, 0, 0);
    __builtin_amdgcn_s_setprio(0);
    __builtin_amdgcn_s_barrier();                       // reads of buf d done
  }
#undef STG128

#pragma unroll
  for (int m = 0; m < 4; ++m)
#pragma unroll
    for (int n = 0; n < 3; ++n) {
      int row = m0 + wm * 64 + m * 16 + g * 4;
      int col = n0 + wn * 48 + n * 16 + c;
      float sc = (SCALEQ && col < 4096) ? QSCALE : 1.0f;
#pragma unroll
      for (int r = 0; r < 4; ++r) {
        float x = acc[m][n][r] * sc;
        if (CBF16) ((u16*)C)[(size_t)(row + r) * N + col] = f2bf(x);
        else       ((float*)C)[(size_t)(row + r) * N + col] = x;
      }
    }
}

// ---------------- bf16 GEMM 256x256 (4-phase, unpinned barriers) ------------
// XCD chunking: grid 16by x 16bx; XCD k owns the 8by x 4bx rectangle.
template <int CBF16, int SCALEQ>
__global__ __launch_bounds__(512, 2) void gemm256(
    const u16* __restrict__ A, const u16* __restrict__ B,
    void* __restrict__ C, int M, int N, int K) {
  __shared__ u16 As[2 * 2 * 8192];   // 64 KB
  __shared__ u16 Bs[2 * 2 * 8192];   // 64 KB
  const int t = threadIdx.x;
  const int w = t >> 6, l = t & 63;
  const int g = l >> 4, c = l & 15;
  const int wm = w >> 2, wn = w & 3;

  const int xcd = blockIdx.x & 7;
  const int idx = blockIdx.x >> 3;           // 0..31
  const int by = (xcd >> 2) * 8 + (idx >> 2);
  const int bx = (xcd & 3) * 4 + (idx & 3);
  const int m0 = by * 256, n0 = bx * 256;

  const int gsrc = (l & 7) ^ (l >> 3);
  const u16* pA = A + (size_t)(m0 + w * 8 + (l >> 3)) * K + gsrc * 8;
  const u16* pB = B + (size_t)(n0 + w * 8 + (l >> 3)) * K + gsrc * 8;

#define STG_A(h, tt) do { int d_ = (tt) & 1;                                    \
    gload16(pA + (size_t)((h) * 128) * K + (tt) * 64,                           \
            &As[(d_ * 2 + (h)) * 8192 + w * 512]);                              \
    gload16(pA + (size_t)((h) * 128 + 64) * K + (tt) * 64,                      \
            &As[(d_ * 2 + (h)) * 8192 + 4096 + w * 512]); } while (0)
#define STG_B(h, tt) do { int d_ = (tt) & 1;                                    \
    gload16(pB + (size_t)((h) * 128) * K + (tt) * 64,                           \
            &Bs[(d_ * 2 + (h)) * 8192 + w * 512]);                              \
    gload16(pB + (size_t)((h) * 128 + 64) * K + (tt) * 64,                      \
            &Bs[(d_ * 2 + (h)) * 8192 + 4096 + w * 512]); } while (0)

  const u16* aRd = &As[wm * 8192 + c * 64];
  const u16* bRd = &Bs[(wn >> 1) * 8192 + ((wn & 1) * 64 + c) * 64];
  const int xr0 = ((0 + g) ^ (c & 7)) << 3;
  const int xr1 = ((4 + g) ^ (c & 7)) << 3;

  const f32x4 fz = {0.f, 0.f, 0.f, 0.f};
  f32x4 acc[8][4];
#pragma unroll
  for (int mi = 0; mi < 8; ++mi)
#pragma unroll
    for (int nj = 0; nj < 4; ++nj) acc[mi][nj] = fz;

  const int nkt = K >> 6;
  STG_A(0, 0); STG_A(1, 0); STG_B(0, 0); STG_B(1, 0);
  STG_B(0, 1); STG_B(1, 1);
  asm volatile("s_waitcnt vmcnt(4)" ::: "memory");
  __builtin_amdgcn_sched_barrier(0);
  __builtin_amdgcn_s_barrier();

  for (int tt = 0; tt < nkt; ++tt) {
    const int d = tt & 1;
    const u16* aT = aRd + d * 16384;
    const u16* bT = bRd + d * 16384;
    bf16x8 av[4][2], b01[2][2], b23[2][2];

    // ---- P0: A-lo + B01; stage A0(t+1)
#pragma unroll
    for (int m = 0; m < 4; ++m) {
      av[m][0] = *(const bf16x8*)(aT + m * 1024 + xr0);
      av[m][1] = *(const bf16x8*)(aT + m * 1024 + xr1);
    }
#pragma unroll
    for (int n = 0; n < 2; ++n) {
      b01[n][0] = *(const bf16x8*)(bT + n * 1024 + xr0);
      b01[n][1] = *(const bf16x8*)(bT + n * 1024 + xr1);
    }
    if (tt + 1 < nkt) STG_A(0, tt + 1);
    __builtin_amdgcn_s_barrier();
    __builtin_amdgcn_s_setprio(1);
#pragma unroll
    for (int kk = 0; kk < 2; ++kk)
#pragma unroll
      for (int m = 0; m < 4; ++m)
#pragma unroll
        for (int n = 0; n < 2; ++n)
          acc[m][n] = __builtin_amdgcn_mfma_f32_16x16x32_bf16(
              av[m][kk], b01[n][kk], acc[m][n], 0, 0, 0);
    __builtin_amdgcn_s_setprio(0);
    __builtin_amdgcn_s_barrier();

    // ---- P1: B23; stage A1(t+1)
#pragma unroll
    for (int n = 0; n < 2; ++n) {
      b23[n][0] = *(const bf16x8*)(bT + (2 + n) * 1024 + xr0);
      b23[n][1] = *(const bf16x8*)(bT + (2 + n) * 1024 + xr1);
    }
    if (tt + 1 < nkt) STG_A(1, tt + 1);
    __builtin_amdgcn_s_barrier();
    __builtin_amdgcn_s_setprio(1);
#pragma unroll
    for (int kk = 0; kk < 2; ++kk)
#pragma unroll
      for (int m = 0; m < 4; ++m)
#pragma unroll
        for (int n = 0; n < 2; ++n)
          acc[m][2 + n] = __builtin_amdgcn_mfma_f32_16x16x32_bf16(
              av[m][kk], b23[n][kk], acc[m][2 + n], 0, 0, 0);
    __builtin_amdgcn_s_setprio(0);
    __builtin_amdgcn_s_barrier();

    // ---- P2: A-hi; stage B0(t+2)
#pragma unroll
    for (int m = 0; m < 4; ++m) {
      av[m][0] = *(const bf16x8*)(aT + (4 + m) * 1024 + xr0);
      av[m][1] = *(const bf16x8*)(aT + (4 + m) * 1024 + xr1);
    }
    if (tt + 2 < nkt) STG_B(0, tt + 2);
    __builtin_amdgcn_s_barrier();
    __builtin_amdgcn_s_setprio(1);
#pragma unroll
    for (int kk = 0; kk < 2; ++kk)
#pragma unroll
      for (int m = 0; m < 4; ++m)
#pragma unroll
        for (int n = 0; n < 2; ++n)
          acc[4 + m][2 + n] = __builtin_amdgcn_mfma_f32_16x16x32_bf16(
              av[m][kk], b23[n][kk], acc[4 + m][2 + n], 0, 0, 0);
    __builtin_amdgcn_s_setprio(0);
    __builtin_amdgcn_s_barrier();

    // ---- P3: stage B1(t+2); counted vmcnt
    if (tt + 2 < nkt) STG_B(1, tt + 2);
    if (tt < nkt - 2) asm volatile("s_waitcnt vmcnt(4)" ::: "memory");
    else              asm volatile("s_waitcnt vmcnt(0)" ::: "memory");
    __builtin_amdgcn_sched_barrier(0);
    __builtin_amdgcn_s_barrier();
    __builtin_amdgcn_s_setprio(1);
#pragma unroll
    for (int kk = 0; kk < 2; ++kk)
#pragma unroll
      for (int m = 0; m < 4; ++m)
#pragma unroll
        for (int n = 0; n < 2; ++n)
          acc[4 + m][n] = __builtin_amdgcn_mfma_f32_16x16x32_bf16(
              av[m][kk], b01[n][kk], acc[4 + m][n], 0, 0, 0);
    __builtin_amdgcn_s_setprio(0);
    __builtin_amdgcn_s_barrier();
  }
#undef STG_A
#undef STG_B

#pragma unroll
  for (int mi = 0; mi < 8; ++mi)
#pragma unroll
    for (int nj = 0; nj < 4; ++nj) {
      int row = m0 + wm * 128 + mi * 16 + g * 4;
      int col = n0 + wn * 64 + nj * 16 + c;
      float sc = (SCALEQ && col < 4096) ? QSCALE : 1.0f;
#pragma unroll
      for (int r = 0; r < 4; ++r) {
        float x = acc[mi][nj][r] * sc;
        if (CBF16) ((u16*)C)[(size_t)(row + r) * N + col] = f2bf(x);
        else       ((float*)C)[(size_t)(row + r) * N + col] = x;
      }
    }
}

// ---------------- flash attention v2 (full, GQA) ----------------
__global__ __launch_bounds__(512, 4) void attn_fwd2(
    const u16* __restrict__ qkv, const u16* __restrict__ vtg,
    u16* __restrict__ out) {
  __shared__ u16 Ks[2][64 * 128];      // [key][d-chunk ^ (key&15)]
  __shared__ u16 Vs[2][128 * 64];      // [d][key-chunk ^ (d&7)]
  __shared__ u16 Ps[8][16 * 64];       // per-wave [q][key-chunk16 ^ (q&7)]
  const int t = threadIdx.x;
  const int w = t >> 6, lane = t & 63;
  const int g = lane >> 4, c = lane & 15;
  const int bh = blockIdx.y;
  const int b = bh >> 5, h = bh & 31, kvh = h >> 2;
  const int q0 = blockIdx.x * 128 + w * 16;

  bf16x8 qf[4];
#pragma unroll
  for (int kk = 0; kk < 4; ++kk)
    qf[kk] = *(const bf16x8*)&qkv[(size_t)((q0 + c) * 2 + b) * QKVC + h * 128 + kk * 32 + g * 8];

  const f32x4 fz = {0.f, 0.f, 0.f, 0.f};
  f32x4 acc[8];
#pragma unroll
  for (int db = 0; db < 8; ++db) acc[db] = fz;
  float m_ = -__builtin_inff(), l_ = 0.f;

  const int w4g = w * 4 + g;
  const u16* pK = qkv + (size_t)b * QKVC + 4096 + kvh * 128 + (size_t)((c ^ w4g) & 15) * 8;
  const int vrow = w * 8 + (lane >> 3);
  const u16* pV = vtg + (size_t)(b * 8 + kvh) * 128 * SEQ + (size_t)((lane & 7) ^ (lane >> 3)) * 8;

  auto stage = [&](int bufi, int kv0) {
#pragma unroll
    for (int j = 0; j < 2; ++j)
      gload16(pK + (size_t)(kv0 + j * 32 + w4g) * (2 * QKVC), &Ks[bufi][(j * 8 + w) * 512]);
#pragma unroll
    for (int j = 0; j < 2; ++j)
      gload16(pV + (size_t)(j * 64 + vrow) * SEQ + kv0, &Vs[bufi][(j * 8 + w) * 512]);
  };

  stage(0, 0);
  int buf = 0;
  for (int kv0 = 0; kv0 < SEQ; kv0 += 64) {
    __syncthreads();
    if (kv0 + 64 < SEQ) stage(buf ^ 1, kv0 + 64);

    f32x4 st[4];
    __builtin_amdgcn_s_setprio(1);
#pragma unroll
    for (int kf = 0; kf < 4; ++kf) {
      const u16* kr = &Ks[buf][(kf * 16 + c) * 128];
      bf16x8 kfr[4];
#pragma unroll
      for (int kk = 0; kk < 4; ++kk)
        kfr[kk] = *(const bf16x8*)&kr[(((kk * 4 + g) ^ c) & 15) * 8];
      f32x4 s = fz;
#pragma unroll
      for (int kk = 0; kk < 4; ++kk)
        s = __builtin_amdgcn_mfma_f32_16x16x32_bf16(kfr[kk], qf[kk], s, 0, 0, 0);
      st[kf] = s;
    }
    __builtin_amdgcn_s_setprio(0);

    float mloc = st[0][0];
#pragma unroll
    for (int kf = 0; kf < 4; ++kf)
#pragma unroll
      for (int r = 0; r < 4; ++r) mloc = fmaxf(mloc, st[kf][r]);
    mloc = fmaxf(mloc, __shfl_xor(mloc, 16));
    mloc = fmaxf(mloc, __shfl_xor(mloc, 32));
    if (!__all(mloc - m_ <= 8.0f)) {
      float mnew = fmaxf(m_, mloc);
      float alpha = __builtin_amdgcn_exp2f(m_ - mnew);
      l_ *= alpha;
      f32x4 av;
#pragma unroll
      for (int r = 0; r < 4; ++r) av[r] = __shfl(alpha, g * 4 + r);
#pragma unroll
      for (int db = 0; db < 8; ++db) acc[db] *= av;
      m_ = mnew;
    }
    float ps = 0.f;
#pragma unroll
    for (int kf = 0; kf < 4; ++kf) {
      u16x4 pk;
#pragma unroll
      for (int r = 0; r < 4; ++r) {
        float p = __builtin_amdgcn_exp2f(st[kf][r] - m_);
        ps += p;
        pk[r] = f2bf(p);
      }
      *(u16x4*)&Ps[w][c * 64 + ((((kf * 2 + (g >> 1)) ^ (c & 7)) << 3) | ((g & 1) << 2))] = pk;
    }
    ps += __shfl_xor(ps, 16);
    ps += __shfl_xor(ps, 32);
    l_ += ps;

    bf16x8 pa0 = *(const bf16x8*)&Ps[w][c * 64 + (((0 + g) ^ (c & 7)) << 3)];
    bf16x8 pa1 = *(const bf16x8*)&Ps[w][c * 64 + (((4 + g) ^ (c & 7)) << 3)];
    __builtin_amdgcn_s_setprio(1);
#pragma unroll
    for (int db = 0; db < 8; ++db) {
      const u16* vr = &Vs[buf][(db * 16 + c) * 64];
      bf16x8 v0 = *(const bf16x8*)&vr[(((0 + g) ^ (c & 7)) << 3)];
      bf16x8 v1 = *(const bf16x8*)&vr[(((4 + g) ^ (c & 7)) << 3)];
      acc[db] = __builtin_amdgcn_mfma_f32_16x16x32_bf16(pa0, v0, acc[db], 0, 0, 0);
      acc[db] = __builtin_amdgcn_mfma_f32_16x16x32_bf16(pa1, v1, acc[db], 0, 0, 0);
    }
    __builtin_amdgcn_s_setprio(0);
    buf ^= 1;
  }

  float linv = __builtin_amdgcn_rcpf(l_);
  f32x4 il;
#pragma unroll
  for (int r = 0; r < 4; ++r) il[r] = __shfl(linv, g * 4 + r);
#pragma unroll
  for (int db = 0; db < 8; ++db) {
#pragma unroll
    for (int r = 0; r < 4; ++r) {
      int s = q0 + g * 4 + r;
      out[(size_t)(s * 2 + b) * DM + h * 128 + db * 16 + c] = f2bf(acc[db][r] * il[r]);
    }
  }
}

// ---------------------------------------------------------------------------
extern "C" void kernel_launch(void* const* d_in, const int* in_sizes, int n_in,
                              void* d_out, int out_size, void* d_ws, size_t ws_size,
                              hipStream_t stream) {
  const float* hidden = (const float*)d_in[0];
  const float* w_qkv  = (const float*)d_in[1];
  const float* w_o    = (const float*)d_in[2];
  float* outp = (float*)d_out;

  const size_t SZ_X  = (size_t)NROWS * DM * 2;     // 32 MB
  const size_t SZ_WQ = (size_t)QKVC * DM * 2;      // 48 MB
  const size_t SZ_WO = (size_t)DM * DM * 2;        // 32 MB
  const size_t SZ_QKV = (size_t)NROWS * QKVC * 2;  // 48 MB
  if (ws_size < SZ_X + SZ_WQ + SZ_WO + SZ_QKV) return;  // 160 MB

  char* ws = (char*)d_ws;
  u16* Xb    = (u16*)ws;
  u16* WqkvT = (u16*)(ws + SZ_X);
  u16* WoT   = (u16*)(ws + SZ_X + SZ_WQ);
  u16* QKVb  = (u16*)(ws + SZ_X + SZ_WQ + SZ_WO);
  u16* VtG   = WqkvT;  // reuse: WqkvT dead after GEMM1 (V^T is 8 MB < 48 MB)
  u16* Attn  = Xb;     // reuse: Xb dead after GEMM1

  conv_f32_bf16<<<(NROWS * (size_t)DM) / 2048, 256, 0, stream>>>(hidden, Xb);
  transpose_f32_bf16<<<dim3(QKVC / 64, DM / 64), 256, 0, stream>>>(w_qkv, WqkvT, DM, QKVC);
  transpose_f32_bf16<<<dim3(DM / 64, DM / 64), 256, 0, stream>>>(w_o, WoT, DM, DM);
  // qkv = X @ Wqkv (q pre-scaled); 128x192 tiles -> 32*32 = 1024 blocks
  gemm128<1, 1><<<1024, 512, 0, stream>>>(Xb, WqkvT, QKVb, NROWS, QKVC, DM);
  // V -> V^T
  vtrans<<<dim3(SEQ / 64, 2, 16), 256, 0, stream>>>(QKVb, VtG);
  // attention
  attn_fwd2<<<dim3(SEQ / 128, BATCH * 32), 512, 0, stream>>>(QKVb, VtG, Attn);
  // out = attn @ w_o (fp32); 256x256 tiles -> 256 blocks (1 perfect round)
  gemm256<0, 0><<<256, 512, 0, stream>>>(Attn, WoT, outp, NROWS, DM, DM);
}